// Round 14
// baseline (256.564 us; speedup 1.0000x reference)
//
#include <hip/hip_runtime.h>
#include <hip/hip_bf16.h>
#include <stdint.h>

// Problem constants: B=4, N=4096, C=1024, H=16, d=64
typedef __attribute__((ext_vector_type(8))) short bf16x8;
typedef __attribute__((ext_vector_type(4))) short bf16x4;
typedef __attribute__((ext_vector_type(4))) float f32x4;
typedef __attribute__((ext_vector_type(4))) int   i32x4;

static __device__ __forceinline__ short f2bs(float f) {
  __hip_bfloat16 h = __float2bfloat16(f);
  return __builtin_bit_cast(short, h);
}

__device__ __forceinline__ void gload_lds16(const void* g, void* l) {
  auto* gp = reinterpret_cast<__attribute__((address_space(1))) uint32_t*>((uintptr_t)g);
  auto* lp = reinterpret_cast<__attribute__((address_space(3))) uint32_t*>((uintptr_t)l);
  __builtin_amdgcn_global_load_lds(gp, lp, 16, 0, 0);
}

// ---------------------------------------------------------------------------
// Layouts (both produced by us):
//  A'' per 64-token group g: [ks 32][frag 4][fr 16][ko 32] bf16 (128 KB each).
//    GEMM row r = h*4 + g16 (h = head, g16 = n16 within group), f = r>>4,
//    fr = r&15; k = tl*64 + dd, ks = k>>5, ko = k&31.
//  W'' (R12 layout, verified): col-tile ct = col>>7:
//    elem = ct*131072 + ks*4096 + ((col>>4)&7)*512 + (col&15)*32 + ko.
// ---------------------------------------------------------------------------

// ---------------------------------------------------------------------------
// Kernel 1: per-token head-mix attention + fused W fp32->bf16 (core verified;
// only A-store addressing changed to the A'' group-blocked layout).
// ---------------------------------------------------------------------------
__global__ __launch_bounds__(256) void attn_kernel(
    const float* __restrict__ x, const float* __restrict__ y,
    __hip_bfloat16* __restrict__ A,
    const float* __restrict__ W, __hip_bfloat16* __restrict__ Wb)
{
  if (blockIdx.x < 1024) {
    const int i = (blockIdx.x * 256 + threadIdx.x) * 4;   // flat [n][k], k%4==0
    const float4 v = *(const float4*)(W + i);
    const int nW = i >> 10, kW = i & 1023;
    const size_t o = (size_t)(nW >> 7) * 131072 + (size_t)(kW >> 5) * 4096
                   + (size_t)((nW >> 4) & 7) * 512 + (nW & 15) * 32 + (kW & 31);
    Wb[o + 0] = __float2bfloat16(v.x);
    Wb[o + 1] = __float2bfloat16(v.y);
    Wb[o + 2] = __float2bfloat16(v.z);
    Wb[o + 3] = __float2bfloat16(v.w);
  }

  const int wid  = threadIdx.x >> 6;
  const int lane = threadIdx.x & 63;
  const int tok  = blockIdx.x * 4 + wid;        // 0..16383

  const float* xr = x + (size_t)tok * 1024;
  const float* yr = y + (size_t)tok * 1024;

  const int c  = lane & 15;
  const int qq = lane >> 4;

  const int fbase = c * 64 + qq * 8;
  bf16x8 yf[2], xf[2];
  #pragma unroll
  for (int kk = 0; kk < 2; ++kk) {
    const float4 a0 = *(const float4*)(yr + fbase + kk * 32);
    const float4 a1 = *(const float4*)(yr + fbase + kk * 32 + 4);
    const float4 b0 = *(const float4*)(xr + fbase + kk * 32);
    const float4 b1 = *(const float4*)(xr + fbase + kk * 32 + 4);
    yf[kk] = bf16x8{f2bs(a0.x), f2bs(a0.y), f2bs(a0.z), f2bs(a0.w),
                    f2bs(a1.x), f2bs(a1.y), f2bs(a1.z), f2bs(a1.w)};
    xf[kk] = bf16x8{f2bs(b0.x), f2bs(b0.y), f2bs(b0.z), f2bs(b0.w),
                    f2bs(b1.x), f2bs(b1.y), f2bs(b1.z), f2bs(b1.w)};
  }

  f32x4 acc = {0.f, 0.f, 0.f, 0.f};
  acc = __builtin_amdgcn_mfma_f32_16x16x32_bf16(yf[0], xf[0], acc, 0, 0, 0);
  acc = __builtin_amdgcn_mfma_f32_16x16x32_bf16(yf[1], xf[1], acc, 0, 0, 0);

  float sc[4];
  #pragma unroll
  for (int r = 0; r < 4; ++r) sc[r] = acc[r] * 0.125f;
  float mx = fmaxf(fmaxf(sc[0], sc[1]), fmaxf(sc[2], sc[3]));
  mx = fmaxf(mx, __shfl_xor(mx, 16));
  mx = fmaxf(mx, __shfl_xor(mx, 32));
  float e[4];
  #pragma unroll
  for (int r = 0; r < 4; ++r) e[r] = __expf(sc[r] - mx);
  float sm = (e[0] + e[1]) + (e[2] + e[3]);
  sm += __shfl_xor(sm, 16);
  sm += __shfl_xor(sm, 32);
  const float inv = 1.0f / sm;
  float p[4];
  #pragma unroll
  for (int r = 0; r < 4; ++r) p[r] = e[r] * inv;

  f32x4 o[4];
  #pragma unroll
  for (int q = 0; q < 4; ++q) o[q] = f32x4{0.f, 0.f, 0.f, 0.f};

#if __has_builtin(__builtin_amdgcn_mfma_f32_16x16x16bf16_1k)
  const bf16x4 pa = {f2bs(p[0]), f2bs(p[1]), f2bs(p[2]), f2bs(p[3])};
  #pragma unroll
  for (int q = 0; q < 4; ++q) {
    bf16x4 bq;
    #pragma unroll
    for (int j = 0; j < 4; ++j)
      bq[j] = f2bs(yr[(qq * 4 + j) * 64 + q * 16 + c]);
    o[q] = __builtin_amdgcn_mfma_f32_16x16x16bf16_1k(pa, bq, o[q], 0, 0, 0);
  }
#else
  const int u0 = ((int)(unsigned short)f2bs(p[1]) << 16) | (unsigned short)f2bs(p[0]);
  const int u1 = ((int)(unsigned short)f2bs(p[3]) << 16) | (unsigned short)f2bs(p[2]);
  const int s0 = c + 32 * qq;
  int a0 = __shfl(u0, s0), a1 = __shfl(u1, s0);
  int a2 = __shfl(u0, s0 + 16), a3 = __shfl(u1, s0 + 16);
  const bool valid = (qq < 2);
  if (!valid) { a0 = 0; a1 = 0; a2 = 0; a3 = 0; }
  const bf16x8 a8 = __builtin_bit_cast(bf16x8, i32x4{a0, a1, a2, a3});
  #pragma unroll
  for (int q = 0; q < 4; ++q) {
    bf16x8 b8;
    #pragma unroll
    for (int j = 0; j < 8; ++j) {
      const int g = (qq * 8 + j) & 15;
      const float v = yr[g * 64 + q * 16 + c];
      b8[j] = valid ? f2bs(v) : (short)0;
    }
    o[q] = __builtin_amdgcn_mfma_f32_16x16x32_bf16(a8, b8, o[q], 0, 0, 0);
  }
#endif

  // ---- store O into group-blocked A'' ----
  // group g = tok>>6; tl = tok&15; g16 = (tok>>4)&3; h = qq*4+r.
  // elem = g*65536 + (tl*2 + (q>>1))*2048 + (h>>2)*512 + ((h&3)*4+g16)*32
  //        + (q&1)*16 + c;   h>>2 == qq, h&3 == r.
  const size_t base3 = (size_t)(tok >> 6) * 65536
                     + (size_t)(tok & 15) * 4096
                     + (size_t)qq * 512
                     + (size_t)((tok >> 4) & 3) * 32 + c;
  #pragma unroll
  for (int q = 0; q < 4; ++q)
    #pragma unroll
    for (int r = 0; r < 4; ++r)
      A[base3 + (q >> 1) * 2048 + r * 128 + (q & 1) * 16] =
          __float2bfloat16(o[q][r]);
}

// ---------------------------------------------------------------------------
// Kernel 2: A-panel-resident GEMM  out = A''[M,K] * W''[Nn,K]^T + bias.
// 256 blocks (1/CU) x 512 thr (8 waves, 2/SIMD). Each block owns 64 GEMM
// rows (one token group): stages the whole 128 KB A-panel into LDS ONCE
// (16 linear gload_lds16 — layout already fragment-blocked), one barrier,
// then a K-loop with NO barriers and NO LDS writes: per wave-step 4 ds_reads
// (contiguous 1 KB frags) + 4 B-loads direct from W'' (L2-resident, depth-2
// register prefetch) + 16 MFMA. Compiler-managed waitcnts throughout.
// 8 waves x 2 passes of 64 cols cover Nn=1024.
// ---------------------------------------------------------------------------
__global__ __launch_bounds__(512, 2) void gemm_fold(
    const __hip_bfloat16* __restrict__ A,   // A'' blocked, 256 groups
    const __hip_bfloat16* __restrict__ Bw,  // W'' blocked, Nn=1024
    const float* __restrict__ bias,         // [Nn]
    float* __restrict__ C)                  // [M=16384, Nn] fp32 row-major
{
  __shared__ char ldsA[131072];             // [ks 32][frag 4][fr 16][ko 32] bf16

  const int tid  = threadIdx.x;             // 0..511
  const int lane = tid & 63;
  const int w    = tid >> 6;                // 8 waves

  const int blk  = blockIdx.x;              // 0..255 = token group
  const int b    = blk >> 6;
  const int n16b = (blk & 63) * 4;

  // ---- stage the 128 KB A-panel (linear copy, layout already final) ----
  {
    const char* src = (const char*)(A + (size_t)blk * 65536);
    #pragma unroll
    for (int i = 0; i < 16; ++i)
      gload_lds16(src + i * 8192 + tid * 16, ldsA + i * 8192 + tid * 16);
    __syncthreads();                        // drains vmcnt; panel visible
  }

  const int fr = lane & 15;
  const int kq = lane >> 4;

  // A ds_read: frag f at step s -> byte s*4096 + f*1024 + fr*64 + kq*16
  const char* aRd = ldsA + fr * 64 + kq * 16;

  #pragma unroll 1
  for (int p = 0; p < 2; ++p) {
    const int c0 = p * 512 + w * 64;        // this wave's 64 cols
    const int ct = c0 >> 7;
    const int cf = (c0 >> 4) & 7;
    // B frag f at step s -> elem ct*131072 + s*4096 + (cf+f)*512 + fr*32 + kq*8
    const __hip_bfloat16* bP = Bw + (size_t)ct * 131072 + (size_t)cf * 512
                             + fr * 32 + kq * 8;

    f32x4 acc[4][4];
    #pragma unroll
    for (int m = 0; m < 4; ++m)
      #pragma unroll
      for (int n = 0; n < 4; ++n) acc[m][n] = f32x4{0.f, 0.f, 0.f, 0.f};

    bf16x8 Af0[4], Af1[4], B0[4], B1[4];

    // prologue: A(0), B(0), B(1)
    #pragma unroll
    for (int f = 0; f < 4; ++f) Af0[f] = *(const bf16x8*)(aRd + f * 1024);
    #pragma unroll
    for (int f = 0; f < 4; ++f) B0[f] = *(const bf16x8*)(bP + f * 512);
    #pragma unroll
    for (int f = 0; f < 4; ++f) B1[f] = *(const bf16x8*)(bP + 4096 + f * 512);

    for (int s = 0; s < 32; s += 2) {
      const int k1 = (s + 1) & 31;
      const int k2 = (s + 2) & 31;
      const int k3 = (s + 3) & 31;
      // parity 0: prefetch A(s+1); MFMA(s) on Af0/B0; prefetch B(s+2)
      #pragma unroll
      for (int f = 0; f < 4; ++f)
        Af1[f] = *(const bf16x8*)(aRd + k1 * 4096 + f * 1024);
      #pragma unroll
      for (int m = 0; m < 4; ++m)
        #pragma unroll
        for (int n = 0; n < 4; ++n)
          acc[m][n] = __builtin_amdgcn_mfma_f32_16x16x32_bf16(Af0[m], B0[n], acc[m][n], 0, 0, 0);
      #pragma unroll
      for (int f = 0; f < 4; ++f)
        B0[f] = *(const bf16x8*)(bP + k2 * 4096 + f * 512);
      // parity 1: prefetch A(s+2); MFMA(s+1) on Af1/B1; prefetch B(s+3)
      #pragma unroll
      for (int f = 0; f < 4; ++f)
        Af0[f] = *(const bf16x8*)(aRd + k2 * 4096 + f * 1024);
      #pragma unroll
      for (int m = 0; m < 4; ++m)
        #pragma unroll
        for (int n = 0; n < 4; ++n)
          acc[m][n] = __builtin_amdgcn_mfma_f32_16x16x32_bf16(Af1[m], B1[n], acc[m][n], 0, 0, 0);
      #pragma unroll
      for (int f = 0; f < 4; ++f)
        B1[f] = *(const bf16x8*)(bP + k3 * 4096 + f * 512);
    }

    // pass epilogue: C/D layout col=lane&15, row=(lane>>4)*4+reg.
    // row_loc = m*16 + kq*4 + rr = h*4 + g16  ->  h = row>>2, g16 = row&3.
    #pragma unroll
    for (int n = 0; n < 4; ++n) {
      const int col = c0 + n * 16 + fr;
      const float bv = bias[col];
      #pragma unroll
      for (int m = 0; m < 4; ++m) {
        #pragma unroll
        for (int rr = 0; rr < 4; ++rr) {
          const int rl = m * 16 + kq * 4 + rr;
          const int orow = b * 4096 + (rl >> 2) * 256 + n16b + (rl & 3);
          C[(size_t)orow * 1024 + col] = acc[m][n][rr] + bv;
        }
      }
    }
  }
}

extern "C" void kernel_launch(void* const* d_in, const int* in_sizes, int n_in,
                              void* d_out, int out_size, void* d_ws, size_t ws_size,
                              hipStream_t stream) {
  const float* x    = (const float*)d_in[0];
  const float* y    = (const float*)d_in[1];
  const float* W    = (const float*)d_in[2];
  const float* bias = (const float*)d_in[3];
  float* out = (float*)d_out;

  // Workspace: A'' (32 MB) + W'' (2 MB)
  __hip_bfloat16* Abuf = (__hip_bfloat16*)d_ws;
  __hip_bfloat16* Wbuf = (__hip_bfloat16*)((char*)d_ws + (size_t)16384 * 1024 * 2);

  attn_kernel<<<4096, 256, 0, stream>>>(x, y, Abuf, W, Wbuf);
  gemm_fold<<<256, 512, 0, stream>>>(Abuf, Wbuf, bias, out);
}

// Round 15
// 75.389 us; speedup vs baseline: 3.4032x; 3.4032x over previous
//
#include <hip/hip_runtime.h>
#include <hip/hip_bf16.h>
#include <stdint.h>

// Problem constants: B=4, N=4096, C=1024, H=16, d=64
typedef __attribute__((ext_vector_type(8))) short bf16x8;
typedef __attribute__((ext_vector_type(4))) short bf16x4;
typedef __attribute__((ext_vector_type(4))) float f32x4;
typedef __attribute__((ext_vector_type(4))) int   i32x4;

static __device__ __forceinline__ short f2bs(float f) {
  __hip_bfloat16 h = __float2bfloat16(f);
  return __builtin_bit_cast(short, h);
}

__device__ __forceinline__ void gload_lds16(const void* g, void* l) {
  auto* gp = reinterpret_cast<__attribute__((address_space(1))) uint32_t*>((uintptr_t)g);
  auto* lp = reinterpret_cast<__attribute__((address_space(3))) uint32_t*>((uintptr_t)l);
  __builtin_amdgcn_global_load_lds(gp, lp, 16, 0, 0);
}

// ---------------------------------------------------------------------------
// Kernel 1: per-token head-mix attention + fused W fp32->bf16 (R8 version:
// A stored in plain GEMM row-major layout [b*4096+h*256+n16][ (n&15)*64+dd ]).
// ---------------------------------------------------------------------------
__global__ __launch_bounds__(256) void attn_kernel(
    const float* __restrict__ x, const float* __restrict__ y,
    __hip_bfloat16* __restrict__ A,
    const float* __restrict__ W, __hip_bfloat16* __restrict__ Wb)
{
  if (blockIdx.x < 1024) {
    const int i = (blockIdx.x * 256 + threadIdx.x) * 4;
    const float4 v = *(const float4*)(W + i);
    Wb[i + 0] = __float2bfloat16(v.x);
    Wb[i + 1] = __float2bfloat16(v.y);
    Wb[i + 2] = __float2bfloat16(v.z);
    Wb[i + 3] = __float2bfloat16(v.w);
  }

  const int wid  = threadIdx.x >> 6;
  const int lane = threadIdx.x & 63;
  const int tok  = blockIdx.x * 4 + wid;        // 0..16383
  const int b    = tok >> 12;
  const int n    = tok & 4095;

  const float* xr = x + (size_t)tok * 1024;
  const float* yr = y + (size_t)tok * 1024;

  const int c  = lane & 15;
  const int qq = lane >> 4;

  const int fbase = c * 64 + qq * 8;
  bf16x8 yf[2], xf[2];
  #pragma unroll
  for (int kk = 0; kk < 2; ++kk) {
    const float4 a0 = *(const float4*)(yr + fbase + kk * 32);
    const float4 a1 = *(const float4*)(yr + fbase + kk * 32 + 4);
    const float4 b0 = *(const float4*)(xr + fbase + kk * 32);
    const float4 b1 = *(const float4*)(xr + fbase + kk * 32 + 4);
    yf[kk] = bf16x8{f2bs(a0.x), f2bs(a0.y), f2bs(a0.z), f2bs(a0.w),
                    f2bs(a1.x), f2bs(a1.y), f2bs(a1.z), f2bs(a1.w)};
    xf[kk] = bf16x8{f2bs(b0.x), f2bs(b0.y), f2bs(b0.z), f2bs(b0.w),
                    f2bs(b1.x), f2bs(b1.y), f2bs(b1.z), f2bs(b1.w)};
  }

  f32x4 acc = {0.f, 0.f, 0.f, 0.f};
  acc = __builtin_amdgcn_mfma_f32_16x16x32_bf16(yf[0], xf[0], acc, 0, 0, 0);
  acc = __builtin_amdgcn_mfma_f32_16x16x32_bf16(yf[1], xf[1], acc, 0, 0, 0);

  float sc[4];
  #pragma unroll
  for (int r = 0; r < 4; ++r) sc[r] = acc[r] * 0.125f;
  float mx = fmaxf(fmaxf(sc[0], sc[1]), fmaxf(sc[2], sc[3]));
  mx = fmaxf(mx, __shfl_xor(mx, 16));
  mx = fmaxf(mx, __shfl_xor(mx, 32));
  float e[4];
  #pragma unroll
  for (int r = 0; r < 4; ++r) e[r] = __expf(sc[r] - mx);
  float sm = (e[0] + e[1]) + (e[2] + e[3]);
  sm += __shfl_xor(sm, 16);
  sm += __shfl_xor(sm, 32);
  const float inv = 1.0f / sm;
  float p[4];
  #pragma unroll
  for (int r = 0; r < 4; ++r) p[r] = e[r] * inv;

  f32x4 o[4];
  #pragma unroll
  for (int q = 0; q < 4; ++q) o[q] = f32x4{0.f, 0.f, 0.f, 0.f};

#if __has_builtin(__builtin_amdgcn_mfma_f32_16x16x16bf16_1k)
  const bf16x4 pa = {f2bs(p[0]), f2bs(p[1]), f2bs(p[2]), f2bs(p[3])};
  #pragma unroll
  for (int q = 0; q < 4; ++q) {
    bf16x4 bq;
    #pragma unroll
    for (int j = 0; j < 4; ++j)
      bq[j] = f2bs(yr[(qq * 4 + j) * 64 + q * 16 + c]);
    o[q] = __builtin_amdgcn_mfma_f32_16x16x16bf16_1k(pa, bq, o[q], 0, 0, 0);
  }
#else
  const int u0 = ((int)(unsigned short)f2bs(p[1]) << 16) | (unsigned short)f2bs(p[0]);
  const int u1 = ((int)(unsigned short)f2bs(p[3]) << 16) | (unsigned short)f2bs(p[2]);
  const int s0 = c + 32 * qq;
  int a0 = __shfl(u0, s0), a1 = __shfl(u1, s0);
  int a2 = __shfl(u0, s0 + 16), a3 = __shfl(u1, s0 + 16);
  const bool valid = (qq < 2);
  if (!valid) { a0 = 0; a1 = 0; a2 = 0; a3 = 0; }
  const bf16x8 a8 = __builtin_bit_cast(bf16x8, i32x4{a0, a1, a2, a3});
  #pragma unroll
  for (int q = 0; q < 4; ++q) {
    bf16x8 b8;
    #pragma unroll
    for (int j = 0; j < 8; ++j) {
      const int g = (qq * 8 + j) & 15;
      const float v = yr[g * 64 + q * 16 + c];
      b8[j] = valid ? f2bs(v) : (short)0;
    }
    o[q] = __builtin_amdgcn_mfma_f32_16x16x32_bf16(a8, b8, o[q], 0, 0, 0);
  }
#endif

  const size_t base = ((size_t)b * 4096 + (n >> 4)) * 1024 + ((n & 15) << 6) + c;
  #pragma unroll
  for (int q = 0; q < 4; ++q)
    #pragma unroll
    for (int r = 0; r < 4; ++r) {
      const int h = qq * 4 + r;
      A[base + (size_t)h * 262144 + q * 16] = __float2bfloat16(o[q][r]);
    }
}

// ---------------------------------------------------------------------------
// Kernel 2: out[M,Nn] = A[M,K]*Bw[Nn,K]^T + bias.  R3 geometry + RING-4 LDS,
// PREFETCH DISTANCE 3, counted gate vmcnt(4) (never drains until the tail).
// 128x128 tile, BK=32, 512 thr / 8 waves (2M x 4N, wave 64x32, acc[4][2]),
// 64 KB LDS -> 2 blocks/CU. Per body: VM4 (stage s landed, 3 bodies of
// latency cover) -> BAR -> STG(s+3) -> 6 ds_read -> MFMA (compiler waits).
// One barrier per step. 0-conflict swizzle, bijective XCD chunking.
// ---------------------------------------------------------------------------
#define FENCE asm volatile("" ::: "memory")
#define BAR   __builtin_amdgcn_s_barrier()
#define VM4   asm volatile("s_waitcnt vmcnt(4)" ::: "memory")
#define VM2   asm volatile("s_waitcnt vmcnt(2)" ::: "memory")
#define VM0   asm volatile("s_waitcnt vmcnt(0)" ::: "memory")
#define SP1   __builtin_amdgcn_s_setprio(1)
#define SP0   __builtin_amdgcn_s_setprio(0)

__global__ __launch_bounds__(512, 2) void gemm_r4(
    const __hip_bfloat16* __restrict__ A,   // [M=16384, K=1024] bf16
    const __hip_bfloat16* __restrict__ Bw,  // [Nn=1024, K=1024] bf16 (= W^T)
    const float* __restrict__ bias,         // [Nn]
    float* __restrict__ C)                  // [M, Nn] fp32
{
  __shared__ char ldsA[4 * 8192];           // ring-4: [buf][128 rows][64B]
  __shared__ char ldsB[4 * 8192];

  const int tid  = threadIdx.x;             // 0..511
  const int lane = tid & 63;
  const int wid  = tid >> 6;                // 8 waves: 2M x 4N
  const int wr   = wid >> 2;                // 0..1 (64 rows)
  const int wc   = wid & 3;                 // 0..3 (32 cols)

  // bijective XCD chunking: 1024 blocks = 8 XCDs x 128 contiguous tiles
  const int bid = blockIdx.x;
  const int nb  = (bid & 7) * 128 + (bid >> 3);
  const int mBase = (nb >> 3) * 128;
  const int nBase = (nb & 7) * 128;

  // staging: 512 thr x 16B = one full 8KB K-step tile per gload instruction.
  // thread t -> row t>>2 (0..127), phys slot t&3; swizzle slot ^= (row>>1)&3.
  const int srow = tid >> 2;
  const int lcb  = (((tid & 3) ^ ((tid >> 3) & 3)) << 4);
  const char* aS = (const char*)A  + (size_t)(mBase + srow) * 2048 + lcb;
  const char* bS = (const char*)Bw + (size_t)(nBase + srow) * 2048 + lcb;
  char* aD = ldsA + tid * 16;
  char* bD = ldsB + tid * 16;

  // ds_read: row R, k-quad kq -> byte R*64 + (kq ^ ((R>>1)&3))*16
  const int fr = lane & 15;
  const int kq = lane >> 4;
  const int ofk  = ((kq ^ ((fr >> 1) & 3)) << 4);
  const int aOff = (wr * 64 + fr) * 64 + ofk;
  const int bOff = (wc * 32 + fr) * 64 + ofk;

  f32x4 acc[4][2];
  #pragma unroll
  for (int m = 0; m < 4; ++m)
    #pragma unroll
    for (int n = 0; n < 2; ++n) acc[m][n] = f32x4{0.f, 0.f, 0.f, 0.f};

  auto STG = [&](int sp) {
    gload_lds16(aS + sp * 64, aD + ((sp & 3) << 13));
    gload_lds16(bS + sp * 64, bD + ((sp & 3) << 13));
  };

  auto BODY = [&](int s, int gate, bool stg) {
    if (gate == 4) { VM4; } else if (gate == 2) { VM2; } else { VM0; }
    FENCE; BAR; FENCE;
    if (stg) STG(s + 3);
    const char* aB = ldsA + ((s & 3) << 13) + aOff;
    const char* bB = ldsB + ((s & 3) << 13) + bOff;
    bf16x8 Af[4], Bf[2];
    #pragma unroll
    for (int n = 0; n < 2; ++n) Bf[n] = *(const bf16x8*)(bB + n * 1024);
    #pragma unroll
    for (int m = 0; m < 4; ++m) Af[m] = *(const bf16x8*)(aB + m * 1024);
    SP1;
    #pragma unroll
    for (int m = 0; m < 4; ++m)
      #pragma unroll
      for (int n = 0; n < 2; ++n)
        acc[m][n] = __builtin_amdgcn_mfma_f32_16x16x32_bf16(Af[m], Bf[n], acc[m][n], 0, 0, 0);
    SP0;
  };

  // prologue: stage steps 0,1,2 (6 loads in flight)
  STG(0); STG(1); STG(2);

  // bodies 0..27 (4-unrolled for static ring indices), staging s+3
  for (int g = 0; g < 7; ++g) {
    const int s = g * 4;
    BODY(s + 0, 4, true);
    BODY(s + 1, 4, true);
    BODY(s + 2, 4, true);
    BODY(s + 3, 4, true);
  }
  BODY(28, 4, true);    // stages 31; outstanding {29,30,31}
  BODY(29, 4, false);   // VM4 -> 29 done
  BODY(30, 2, false);   // VM2 -> 30 done
  BODY(31, 0, false);   // VM0 -> 31 done

  // epilogue: C/D layout col=lane&15, row=(lane>>4)*4+reg
  #pragma unroll
  for (int n = 0; n < 2; ++n) {
    const int col = nBase + wc * 32 + n * 16 + fr;
    const float bv = bias[col];
    #pragma unroll
    for (int m = 0; m < 4; ++m) {
      const int row0 = mBase + wr * 64 + m * 16 + kq * 4;
      #pragma unroll
      for (int r = 0; r < 4; ++r)
        C[(size_t)(row0 + r) * 1024 + col] = acc[m][n][r] + bv;
    }
  }
}

extern "C" void kernel_launch(void* const* d_in, const int* in_sizes, int n_in,
                              void* d_out, int out_size, void* d_ws, size_t ws_size,
                              hipStream_t stream) {
  const float* x    = (const float*)d_in[0];
  const float* y    = (const float*)d_in[1];
  const float* W    = (const float*)d_in[2];
  const float* bias = (const float*)d_in[3];
  float* out = (float*)d_out;

  // Workspace: A (16384x1024 bf16 = 32 MB) + Wbf16 (2 MB)
  __hip_bfloat16* Abuf = (__hip_bfloat16*)d_ws;
  __hip_bfloat16* Wbuf = (__hip_bfloat16*)((char*)d_ws + (size_t)16384 * 1024 * 2);

  attn_kernel<<<4096, 256, 0, stream>>>(x, y, Abuf, W, Wbuf);
  gemm_r4<<<1024, 512, 0, stream>>>(Abuf, Wbuf, bias, out);
}

// Round 16
// 73.804 us; speedup vs baseline: 3.4763x; 1.0215x over previous
//
#include <hip/hip_runtime.h>
#include <hip/hip_bf16.h>
#include <stdint.h>

// Problem constants: B=4, N=4096, C=1024, H=16, d=64
typedef __attribute__((ext_vector_type(8))) short bf16x8;
typedef __attribute__((ext_vector_type(4))) short bf16x4;
typedef __attribute__((ext_vector_type(4))) float f32x4;
typedef __attribute__((ext_vector_type(4))) int   i32x4;

static __device__ __forceinline__ short f2bs(float f) {
  __hip_bfloat16 h = __float2bfloat16(f);
  return __builtin_bit_cast(short, h);
}

__device__ __forceinline__ void gload_lds16(const void* g, void* l) {
  auto* gp = reinterpret_cast<__attribute__((address_space(1))) uint32_t*>((uintptr_t)g);
  auto* lp = reinterpret_cast<__attribute__((address_space(3))) uint32_t*>((uintptr_t)l);
  __builtin_amdgcn_global_load_lds(gp, lp, 16, 0, 0);
}

// ---------------------------------------------------------------------------
// Kernel 1: per-token head-mix attention + fused W fp32->bf16.
// One wave per token, all-register MFMA path, no LDS. ~90% of memory floor.
// ---------------------------------------------------------------------------
__global__ __launch_bounds__(256) void attn_kernel(
    const float* __restrict__ x, const float* __restrict__ y,
    __hip_bfloat16* __restrict__ A,
    const float* __restrict__ W, __hip_bfloat16* __restrict__ Wb)
{
  if (blockIdx.x < 1024) {
    const int i = (blockIdx.x * 256 + threadIdx.x) * 4;
    const float4 v = *(const float4*)(W + i);
    Wb[i + 0] = __float2bfloat16(v.x);
    Wb[i + 1] = __float2bfloat16(v.y);
    Wb[i + 2] = __float2bfloat16(v.z);
    Wb[i + 3] = __float2bfloat16(v.w);
  }

  const int wid  = threadIdx.x >> 6;
  const int lane = threadIdx.x & 63;
  const int tok  = blockIdx.x * 4 + wid;        // 0..16383
  const int b    = tok >> 12;
  const int n    = tok & 4095;

  const float* xr = x + (size_t)tok * 1024;
  const float* yr = y + (size_t)tok * 1024;

  const int c  = lane & 15;
  const int qq = lane >> 4;

  const int fbase = c * 64 + qq * 8;
  bf16x8 yf[2], xf[2];
  #pragma unroll
  for (int kk = 0; kk < 2; ++kk) {
    const float4 a0 = *(const float4*)(yr + fbase + kk * 32);
    const float4 a1 = *(const float4*)(yr + fbase + kk * 32 + 4);
    const float4 b0 = *(const float4*)(xr + fbase + kk * 32);
    const float4 b1 = *(const float4*)(xr + fbase + kk * 32 + 4);
    yf[kk] = bf16x8{f2bs(a0.x), f2bs(a0.y), f2bs(a0.z), f2bs(a0.w),
                    f2bs(a1.x), f2bs(a1.y), f2bs(a1.z), f2bs(a1.w)};
    xf[kk] = bf16x8{f2bs(b0.x), f2bs(b0.y), f2bs(b0.z), f2bs(b0.w),
                    f2bs(b1.x), f2bs(b1.y), f2bs(b1.z), f2bs(b1.w)};
  }

  f32x4 acc = {0.f, 0.f, 0.f, 0.f};
  acc = __builtin_amdgcn_mfma_f32_16x16x32_bf16(yf[0], xf[0], acc, 0, 0, 0);
  acc = __builtin_amdgcn_mfma_f32_16x16x32_bf16(yf[1], xf[1], acc, 0, 0, 0);

  float sc[4];
  #pragma unroll
  for (int r = 0; r < 4; ++r) sc[r] = acc[r] * 0.125f;
  float mx = fmaxf(fmaxf(sc[0], sc[1]), fmaxf(sc[2], sc[3]));
  mx = fmaxf(mx, __shfl_xor(mx, 16));
  mx = fmaxf(mx, __shfl_xor(mx, 32));
  float e[4];
  #pragma unroll
  for (int r = 0; r < 4; ++r) e[r] = __expf(sc[r] - mx);
  float sm = (e[0] + e[1]) + (e[2] + e[3]);
  sm += __shfl_xor(sm, 16);
  sm += __shfl_xor(sm, 32);
  const float inv = 1.0f / sm;
  float p[4];
  #pragma unroll
  for (int r = 0; r < 4; ++r) p[r] = e[r] * inv;

  f32x4 o[4];
  #pragma unroll
  for (int q = 0; q < 4; ++q) o[q] = f32x4{0.f, 0.f, 0.f, 0.f};

#if __has_builtin(__builtin_amdgcn_mfma_f32_16x16x16bf16_1k)
  const bf16x4 pa = {f2bs(p[0]), f2bs(p[1]), f2bs(p[2]), f2bs(p[3])};
  #pragma unroll
  for (int q = 0; q < 4; ++q) {
    bf16x4 bq;
    #pragma unroll
    for (int j = 0; j < 4; ++j)
      bq[j] = f2bs(yr[(qq * 4 + j) * 64 + q * 16 + c]);
    o[q] = __builtin_amdgcn_mfma_f32_16x16x16bf16_1k(pa, bq, o[q], 0, 0, 0);
  }
#else
  const int u0 = ((int)(unsigned short)f2bs(p[1]) << 16) | (unsigned short)f2bs(p[0]);
  const int u1 = ((int)(unsigned short)f2bs(p[3]) << 16) | (unsigned short)f2bs(p[2]);
  const int s0 = c + 32 * qq;
  int a0 = __shfl(u0, s0), a1 = __shfl(u1, s0);
  int a2 = __shfl(u0, s0 + 16), a3 = __shfl(u1, s0 + 16);
  const bool valid = (qq < 2);
  if (!valid) { a0 = 0; a1 = 0; a2 = 0; a3 = 0; }
  const bf16x8 a8 = __builtin_bit_cast(bf16x8, i32x4{a0, a1, a2, a3});
  #pragma unroll
  for (int q = 0; q < 4; ++q) {
    bf16x8 b8;
    #pragma unroll
    for (int j = 0; j < 8; ++j) {
      const int g = (qq * 8 + j) & 15;
      const float v = yr[g * 64 + q * 16 + c];
      b8[j] = valid ? f2bs(v) : (short)0;
    }
    o[q] = __builtin_amdgcn_mfma_f32_16x16x32_bf16(a8, b8, o[q], 0, 0, 0);
  }
#endif

  const size_t base = ((size_t)b * 4096 + (n >> 4)) * 1024 + ((n & 15) << 6) + c;
  #pragma unroll
  for (int q = 0; q < 4; ++q)
    #pragma unroll
    for (int r = 0; r < 4; ++r) {
      const int h = qq * 4 + r;
      A[base + (size_t)h * 262144 + q * 16] = __float2bfloat16(o[q][r]);
    }
}

// ---------------------------------------------------------------------------
// Kernel 2: out[M,Nn] = A[M,K] * Bw[Nn,K]^T + bias, fp32 out.
// BM=256, BN=128, BK=32, 256 threads (4 waves 2Mx2N), wave tile 128x64,
// ring-3 LDS (72 KB) -> 2 blocks/CU. Per K-step:
//   VM6 -> BAR -> STG(s+2) -> 12 ds_read -> lgkm0 -> 32 MFMA (setprio)
// Counted gate covers 2 full steps; vmcnt never drains in the loop.
// Grid 512; xcd = mg%8 so each A-panel's 8 N-blocks share one XCD L2.
// Best-measured configuration of the session (73.9 us total).
// ---------------------------------------------------------------------------
#define FENCE asm volatile("" ::: "memory")
#define BAR   __builtin_amdgcn_s_barrier()
#define LGKM0 asm volatile("s_waitcnt lgkmcnt(0)" ::: "memory")
#define VM6   asm volatile("s_waitcnt vmcnt(6)" ::: "memory")
#define VM0   asm volatile("s_waitcnt vmcnt(0)" ::: "memory")
#define SB0   __builtin_amdgcn_sched_barrier(0)
#define SP1   __builtin_amdgcn_s_setprio(1)
#define SP0   __builtin_amdgcn_s_setprio(0)

__global__ __launch_bounds__(256, 2) void gemm_wt(
    const __hip_bfloat16* __restrict__ A,   // [M,K] row-major bf16
    const __hip_bfloat16* __restrict__ Bw,  // [Nn,K] row-major bf16 (= W^T)
    const float* __restrict__ bias,         // [Nn]
    float* __restrict__ C)                  // [M,Nn] fp32
{
  __shared__ char ldsA[3 * 16384];          // ring-3: [buf][256 rows][64B]
  __shared__ char ldsB[3 * 8192];           // ring-3: [buf][128 rows][64B]

  const int tid  = threadIdx.x;             // 0..255
  const int lane = tid & 63;
  const int wid  = tid >> 6;                // 4 waves: 2M x 2N
  const int wr   = wid >> 1;                // 0..1 (128 rows)
  const int wc   = wid & 1;                 // 0..1 (64 cols)

  // Grid 512: xcd = bid&7 = mg%8 -> all 8 N-blocks of an A-panel on one XCD.
  const int bid   = blockIdx.x;
  const int mg    = (bid & 7) | (((bid >> 3) & 7) << 3);  // 0..63
  const int nt    = (bid >> 6) & 7;                       // 0..7
  const int mBase = mg * 256;
  const int nBase = nt * 128;

  // staging: linear LDS dest, pre-swizzled global source.
  // thread t -> row (t>>2) within a 64-row issue band, phys slot t&3;
  // swizzle involution: slot ^= (row>>1)&3
  const int srow = tid >> 2;                // 0..63
  const int lcb  = (((tid & 3) ^ ((srow >> 1) & 3)) << 4);
  const char* aS0 = (const char*)A  + (size_t)(mBase + srow)       * 2048 + lcb;
  const char* aS1 = (const char*)A  + (size_t)(mBase + 64 + srow)  * 2048 + lcb;
  const char* aS2 = (const char*)A  + (size_t)(mBase + 128 + srow) * 2048 + lcb;
  const char* aS3 = (const char*)A  + (size_t)(mBase + 192 + srow) * 2048 + lcb;
  const char* bS0 = (const char*)Bw + (size_t)(nBase + srow)       * 2048 + lcb;
  const char* bS1 = (const char*)Bw + (size_t)(nBase + 64 + srow)  * 2048 + lcb;

  // ds_read: row R, k-quad kq -> byte R*64 + (kq ^ ((R>>1)&3))*16
  const int fr = lane & 15;
  const int kq = lane >> 4;
  const int fq = kq;
  const int ofk  = ((kq ^ ((fr >> 1) & 3)) << 4);
  const int aOff = (wr * 128 + fr) * 64 + ofk;
  const int bOff = (wc * 64  + fr) * 64 + ofk;

  f32x4 acc[8][4];
  #pragma unroll
  for (int m = 0; m < 8; ++m)
    #pragma unroll
    for (int n = 0; n < 4; ++n) acc[m][n] = f32x4{0.f, 0.f, 0.f, 0.f};

  // stage K-step sp (byte offset sp*64 along K) into ring buffer `buf`
  auto STG = [&](int sp, int buf) {
    const int ko = sp * 64;
    char* aD = ldsA + buf * 16384 + tid * 16;
    char* bD = ldsB + buf * 8192  + tid * 16;
    gload_lds16(aS0 + ko, aD);
    gload_lds16(aS1 + ko, aD + 4096);
    gload_lds16(aS2 + ko, aD + 8192);
    gload_lds16(aS3 + ko, aD + 12288);
    gload_lds16(bS0 + ko, bD);
    gload_lds16(bS1 + ko, bD + 4096);
  };

  // one K-step: gate stage(s) -> barrier -> stage(s+2) -> read -> MFMA
  auto STEP = [&](int s, int rb, bool stg, bool last) {
    if (last) { VM0; } else { VM6; }
    FENCE; BAR; FENCE;
    if (stg) STG(s + 2, (s + 2) % 3);
    const char* aB = ldsA + rb * 16384 + aOff;
    const char* bB = ldsB + rb * 8192  + bOff;
    bf16x8 Af[8], Bf[4];
    #pragma unroll
    for (int n = 0; n < 4; ++n) Bf[n] = *(const bf16x8*)(bB + n * 1024);
    #pragma unroll
    for (int m = 0; m < 8; ++m) Af[m] = *(const bf16x8*)(aB + m * 1024);
    LGKM0; SB0;
    SP1;
    #pragma unroll
    for (int m = 0; m < 8; ++m)
      #pragma unroll
      for (int n = 0; n < 4; ++n)
        acc[m][n] = __builtin_amdgcn_mfma_f32_16x16x32_bf16(Af[m], Bf[n], acc[m][n], 0, 0, 0);
    SP0;
  };

  // prologue: stage steps 0,1 (12 loads in flight)
  STG(0, 0); STG(1, 1);

  for (int t = 0; t < 30; t += 3) {
    STEP(t,     0, true, false);
    STEP(t + 1, 1, true, false);
    STEP(t + 2, 2, true, false);
  }
  STEP(30, 0, false, false);   // gate VM6 -> stage(30) done
  STEP(31, 1, false, true);    // gate VM0 -> stage(31) done

  // epilogue: C/D layout col=lane&15, row=(lane>>4)*4+reg.
  // Overlapped by the co-resident block's K-loop (2 blocks/CU).
  #pragma unroll
  for (int n = 0; n < 4; ++n) {
    const int col = nBase + wc * 64 + n * 16 + fr;
    const float bv = bias[col];
    #pragma unroll
    for (int m = 0; m < 8; ++m) {
      const int row0 = mBase + wr * 128 + m * 16 + fq * 4;
      #pragma unroll
      for (int r = 0; r < 4; ++r)
        C[(size_t)(row0 + r) * 1024 + col] = acc[m][n][r] + bv;
    }
  }
}

extern "C" void kernel_launch(void* const* d_in, const int* in_sizes, int n_in,
                              void* d_out, int out_size, void* d_ws, size_t ws_size,
                              hipStream_t stream) {
  const float* x    = (const float*)d_in[0];
  const float* y    = (const float*)d_in[1];
  const float* W    = (const float*)d_in[2];
  const float* bias = (const float*)d_in[3];
  float* out = (float*)d_out;

  // Workspace: A (16384x1024 bf16 = 32 MB) + Wbf16 (2 MB)
  __hip_bfloat16* Abuf = (__hip_bfloat16*)d_ws;
  __hip_bfloat16* Wbuf = (__hip_bfloat16*)((char*)d_ws + (size_t)16384 * 1024 * 2);

  attn_kernel<<<4096, 256, 0, stream>>>(x, y, Abuf, W, Wbuf);
  gemm_wt<<<512, 256, 0, stream>>>(Abuf, Wbuf, bias, out);
}